// Round 1
// baseline (1962.889 us; speedup 1.0000x reference)
//
#include <hip/hip_runtime.h>
#include <stdint.h>

#define N_TOK 16384
#define KDIM 32
#define DDIM 512
#define FDIM 8
#define TWO_D 1024
#define JCOLS 8192   // 2 tensors (net, gate) * F * D
#define CHUNK 2048
#define NCHUNK 8

typedef unsigned short ushort_t;
typedef __attribute__((ext_vector_type(8))) short short8;   // 8 bf16 = 4 VGPRs (MFMA A/B frag)
typedef __attribute__((ext_vector_type(4))) float f32x4;    // MFMA C/D frag

__device__ inline unsigned short f2bf(float x) {
  union { float f; unsigned int u; } v; v.f = x;
  unsigned int r = v.u + 0x7fffu + ((v.u >> 16) & 1u);  // RNE
  return (unsigned short)(r >> 16);
}
__device__ inline float bflo(unsigned int pk) {
  union { unsigned int u; float f; } v; v.u = pk << 16; return v.f;
}
__device__ inline float bfhi(unsigned int pk) {
  union { unsigned int u; float f; } v; v.u = pk & 0xffff0000u; return v.f;
}

__device__ inline void async_load16(const void* g, void* l) {
  __builtin_amdgcn_global_load_lds(
      (const __attribute__((address_space(1))) unsigned int*)g,
      (__attribute__((address_space(3))) unsigned int*)l, 16, 0, 0);
}

// ---------------------------------------------------------------------------
// K0: transpose-convert net_W,gate_W (F,2D,D) fp32 -> Bc[j][k] bf16, K-major
// ("B^T" layout so GEMM stages both operands identically). j = t*4096+f*512+d.
// ---------------------------------------------------------------------------
__global__ __launch_bounds__(256) void convert_weights(
    const float* __restrict__ net_W, const float* __restrict__ gate_W,
    ushort_t* __restrict__ Bc) {
  const int b = blockIdx.x;          // 2048 = 16 tf * 16 kt * 8 dt
  const int dt = b & 7;
  const int kt = (b >> 3) & 15;
  const int tf = b >> 7;             // 0..15
  const int t = tf >> 3, f = tf & 7;
  const float* src = (t == 0 ? net_W : gate_W) + (size_t)f * TWO_D * DDIM;
  __shared__ float tile[64][65];     // +1 pad: conflict-free transpose
  const int tx = threadIdx.x & 63;
  const int ty = threadIdx.x >> 6;
  #pragma unroll
  for (int i = 0; i < 16; ++i) {
    int kk = i * 4 + ty;
    tile[kk][tx] = src[(size_t)(kt * 64 + kk) * DDIM + dt * 64 + tx];
  }
  __syncthreads();
  #pragma unroll
  for (int i = 0; i < 16; ++i) {
    int dd = i * 4 + ty;
    int j = t * 4096 + f * 512 + dt * 64 + dd;
    Bc[(size_t)j * TWO_D + kt * 64 + tx] = f2bf(tile[tx][dd]);
  }
}

// ---------------------------------------------------------------------------
// K1: per-token prep — sim softmax + argument gather, write inp bf16 [N][1024],
// router softmax -> fn_w [N][8].  HBM-bound: streams routed_tokens (1 GiB).
// ---------------------------------------------------------------------------
__global__ __launch_bounds__(256) void prep_kernel(
    const float* __restrict__ token, const float* __restrict__ routed,
    const float* __restrict__ sim_row, const float* __restrict__ sel_W,
    const float* __restrict__ sel_b, ushort_t* __restrict__ inp,
    float* __restrict__ fn_w) {
  const int n = blockIdx.x;
  const int tid = threadIdx.x;
  // softmax over sim_row[n][0..31] (redundant per thread, L1 broadcast)
  const float* sr = sim_row + (size_t)n * KDIM;
  float s[KDIM];
  float m = -1e30f;
  #pragma unroll
  for (int k = 0; k < KDIM; ++k) { s[k] = sr[k]; m = fmaxf(m, s[k]); }
  float den = 0.f;
  #pragma unroll
  for (int k = 0; k < KDIM; ++k) { s[k] = __expf(s[k] - m); den += s[k]; }
  const float inv = 1.0f / den;

  // argument[d0..d0+1] = sum_k w_k * routed[n][k][d]
  const float2* rb = (const float2*)(routed + (size_t)n * KDIM * DDIM);
  float2 acc = make_float2(0.f, 0.f);
  #pragma unroll
  for (int k = 0; k < KDIM; ++k) {
    float2 r = rb[k * 256 + tid];
    float wk = s[k] * inv;
    acc.x += wk * r.x; acc.y += wk * r.y;
  }
  float2 tv = ((const float2*)(token + (size_t)n * DDIM))[tid];
  unsigned int* row32 = (unsigned int*)(inp + (size_t)n * TWO_D);
  row32[tid]       = (unsigned int)f2bf(tv.x)  | ((unsigned int)f2bf(tv.y)  << 16);
  row32[256 + tid] = (unsigned int)f2bf(acc.x) | ((unsigned int)f2bf(acc.y) << 16);

  // router logits: token @ sel_W (512x8) -> softmax
  float p[FDIM];
  const int d0 = tid * 2;
  #pragma unroll
  for (int f = 0; f < FDIM; ++f)
    p[f] = tv.x * sel_W[d0 * FDIM + f] + tv.y * sel_W[(d0 + 1) * FDIM + f];
  #pragma unroll
  for (int f = 0; f < FDIM; ++f) {
    #pragma unroll
    for (int off = 32; off > 0; off >>= 1)
      p[f] += __shfl_down(p[f], off, 64);
  }
  __shared__ float part[4][FDIM];
  const int lane = tid & 63, wid = tid >> 6;
  if (lane == 0) {
    #pragma unroll
    for (int f = 0; f < FDIM; ++f) part[wid][f] = p[f];
  }
  __syncthreads();
  if (tid == 0) {
    float l[FDIM]; float mm = -1e30f;
    #pragma unroll
    for (int f = 0; f < FDIM; ++f) {
      l[f] = sel_b[f] + part[0][f] + part[1][f] + part[2][f] + part[3][f];
      mm = fmaxf(mm, l[f]);
    }
    float dd = 0.f;
    #pragma unroll
    for (int f = 0; f < FDIM; ++f) { l[f] = __expf(l[f] - mm); dd += l[f]; }
    float id = 1.0f / dd;
    #pragma unroll
    for (int f = 0; f < FDIM; ++f) fn_w[(size_t)n * FDIM + f] = l[f] * id;
  }
}

// ---------------------------------------------------------------------------
// K2: bf16 MFMA GEMM  C[chunk 2048 x 8192] = inp[.,1024] @ Bc^T, 128x128 tile,
// BK=32, 4 waves (2x2), 16x16x32 MFMA, global_load_lds width=16 (m97 pattern).
// Epilogue: +bias, GELU(exact) for net cols / sigmoid for gate cols, bf16 out.
// ---------------------------------------------------------------------------
__global__ __launch_bounds__(256, 2) void gemm_kernel(
    const ushort_t* __restrict__ inp, const ushort_t* __restrict__ Bc,
    const float* __restrict__ net_b, const float* __restrict__ gate_b,
    ushort_t* __restrict__ Cws, int n0) {
  __shared__ __align__(16) ushort_t As[128 * 32];
  __shared__ __align__(16) ushort_t Bs[128 * 32];
  const int tid = threadIdx.x;
  const int bm = blockIdx.x, bn = blockIdx.y;
  const int lane = tid & 63, w = tid >> 6;
  const int wr = w >> 1, wc = w & 1;
  const int r16 = lane & 15, kg = lane >> 4;
  const int row_a = tid >> 2;        // 0..63 (row within half-tile per issue)
  const int c8 = (tid & 3) * 8;      // k-offset (8 bf16 = 16 B chunks)

  f32x4 acc[4][4];
  #pragma unroll
  for (int i = 0; i < 4; ++i)
    #pragma unroll
    for (int j = 0; j < 4; ++j) acc[i][j] = (f32x4){0.f, 0.f, 0.f, 0.f};

  const ushort_t* Ab = inp + (size_t)(n0 + bm * 128) * TWO_D;
  const ushort_t* Bb = Bc + (size_t)(bn * 128) * TWO_D;

  for (int k0 = 0; k0 < TWO_D; k0 += 32) {
    async_load16(Ab + (size_t)row_a * TWO_D + k0 + c8,        (char*)As + tid * 16);
    async_load16(Ab + (size_t)(row_a + 64) * TWO_D + k0 + c8, (char*)As + 4096 + tid * 16);
    async_load16(Bb + (size_t)row_a * TWO_D + k0 + c8,        (char*)Bs + tid * 16);
    async_load16(Bb + (size_t)(row_a + 64) * TWO_D + k0 + c8, (char*)Bs + 4096 + tid * 16);
    __syncthreads();  // drains vmcnt -> LDS tiles ready
    short8 a[4], b[4];
    #pragma unroll
    for (int mt = 0; mt < 4; ++mt)
      a[mt] = *(const short8*)(As + (wr * 64 + mt * 16 + r16) * 32 + kg * 8);
    #pragma unroll
    for (int nt = 0; nt < 4; ++nt)
      b[nt] = *(const short8*)(Bs + (wc * 64 + nt * 16 + r16) * 32 + kg * 8);
    #pragma unroll
    for (int mt = 0; mt < 4; ++mt)
      #pragma unroll
      for (int nt = 0; nt < 4; ++nt)
        acc[mt][nt] = __builtin_amdgcn_mfma_f32_16x16x32_bf16(a[mt], b[nt], acc[mt][nt], 0, 0, 0);
    __syncthreads();  // protect LDS before next stage
  }

  const bool isNet = (bn < 32);  // cols [0,4096) = net, [4096,8192) = gate
  #pragma unroll
  for (int nt = 0; nt < 4; ++nt) {
    const int j = bn * 128 + wc * 64 + nt * 16 + r16;
    const float bj = isNet ? net_b[j] : gate_b[j - 4096];
    #pragma unroll
    for (int mt = 0; mt < 4; ++mt) {
      #pragma unroll
      for (int i = 0; i < 4; ++i) {
        const int nloc = bm * 128 + wr * 64 + mt * 16 + kg * 4 + i;
        float x = acc[mt][nt][i] + bj;
        float y = isNet ? 0.5f * x * (1.0f + erff(x * 0.70710678118f))
                        : 1.0f / (1.0f + __expf(-x));
        Cws[(size_t)nloc * JCOLS + j] = f2bf(y);
      }
    }
  }
}

// ---------------------------------------------------------------------------
// K3: per-token finalize — LN stats from the bf16 gelu values themselves
// (self-consistent, no atomics), then softmax-weighted combine over F.
// ---------------------------------------------------------------------------
__global__ __launch_bounds__(256) void finalize_kernel(
    const ushort_t* __restrict__ Cws, const float* __restrict__ fn_w,
    const float* __restrict__ ln_g, const float* __restrict__ ln_b,
    float* __restrict__ out, int n0) {
  const int nloc = blockIdx.x;
  const int n = n0 + nloc;
  const int tid = threadIdx.x;
  const int lane = tid & 63, wid = tid >> 6;
  const unsigned int* row32 = (const unsigned int*)(Cws + (size_t)nloc * JCOLS);

  float w[FDIM];
  #pragma unroll
  for (int f = 0; f < FDIM; ++f) w[f] = fn_w[(size_t)n * FDIM + f];

  float ux[FDIM], uy[FDIM], ps[FDIM], pq[FDIM];
  #pragma unroll
  for (int f = 0; f < FDIM; ++f) {
    unsigned int pk = row32[f * 256 + tid];          // net half, d0 = 2*tid
    ux[f] = bflo(pk); uy[f] = bfhi(pk);
    ps[f] = ux[f] + uy[f];
    pq[f] = ux[f] * ux[f] + uy[f] * uy[f];
  }
  #pragma unroll
  for (int f = 0; f < FDIM; ++f) {
    #pragma unroll
    for (int off = 32; off > 0; off >>= 1) {
      ps[f] += __shfl_down(ps[f], off, 64);
      pq[f] += __shfl_down(pq[f], off, 64);
    }
  }
  __shared__ float sS[4][FDIM], sQ[4][FDIM];
  if (lane == 0) {
    #pragma unroll
    for (int f = 0; f < FDIM; ++f) { sS[wid][f] = ps[f]; sQ[wid][f] = pq[f]; }
  }
  __syncthreads();

  float op0 = 0.f, op1 = 0.f, og0 = 0.f, og1 = 0.f;
  #pragma unroll
  for (int f = 0; f < FDIM; ++f) {
    float S = sS[0][f] + sS[1][f] + sS[2][f] + sS[3][f];
    float Q = sQ[0][f] + sQ[1][f] + sQ[2][f] + sQ[3][f];
    float mu = S * (1.0f / DDIM);
    float var = Q * (1.0f / DDIM) - mu * mu;
    float rs = rsqrtf(var + 1e-5f);
    float2 g  = ((const float2*)(ln_g + (size_t)f * DDIM))[tid];
    float2 bb = ((const float2*)(ln_b + (size_t)f * DDIM))[tid];
    op0 += w[f] * ((ux[f] - mu) * rs * g.x + bb.x);
    op1 += w[f] * ((uy[f] - mu) * rs * g.y + bb.y);
    unsigned int pk = row32[2048 + f * 256 + tid];   // gate half (offset 4096 bf16)
    og0 += w[f] * bflo(pk);
    og1 += w[f] * bfhi(pk);
  }
  ((float2*)(out + (size_t)n * DDIM))[tid] = make_float2(op0, op1);
  ((float2*)(out + (size_t)N_TOK * DDIM + (size_t)n * DDIM))[tid] = make_float2(og0, og1);
}

// ---------------------------------------------------------------------------
extern "C" void kernel_launch(void* const* d_in, const int* in_sizes, int n_in,
                              void* d_out, int out_size, void* d_ws, size_t ws_size,
                              hipStream_t stream) {
  const float* token  = (const float*)d_in[0];
  const float* routed = (const float*)d_in[1];
  const float* sim    = (const float*)d_in[2];
  const float* selW   = (const float*)d_in[3];
  const float* selb   = (const float*)d_in[4];
  const float* netW   = (const float*)d_in[5];
  const float* netb   = (const float*)d_in[6];
  const float* lng    = (const float*)d_in[7];
  const float* lnb    = (const float*)d_in[8];
  const float* gateW  = (const float*)d_in[9];
  const float* gateb  = (const float*)d_in[10];
  float* out = (float*)d_out;

  // ws layout: Bc 16 MiB | inp 32 MiB | fn_w 0.5 MiB | Cws chunk 32 MiB  (~81 MiB)
  char* p = (char*)d_ws;
  ushort_t* Bc  = (ushort_t*)p; p += (size_t)JCOLS * TWO_D * sizeof(ushort_t);
  ushort_t* inp = (ushort_t*)p; p += (size_t)N_TOK * TWO_D * sizeof(ushort_t);
  float*    fnw = (float*)p;    p += (size_t)N_TOK * FDIM * sizeof(float);
  ushort_t* Cws = (ushort_t*)p; p += (size_t)CHUNK * JCOLS * sizeof(ushort_t);

  hipLaunchKernelGGL(convert_weights, dim3(2048), dim3(256), 0, stream, netW, gateW, Bc);
  hipLaunchKernelGGL(prep_kernel, dim3(N_TOK), dim3(256), 0, stream,
                     token, routed, sim, selW, selb, inp, fnw);
  for (int c = 0; c < NCHUNK; ++c) {
    int n0 = c * CHUNK;
    hipLaunchKernelGGL(gemm_kernel, dim3(CHUNK / 128, JCOLS / 128), dim3(256), 0, stream,
                       inp, Bc, netb, gateb, Cws, n0);
    hipLaunchKernelGGL(finalize_kernel, dim3(CHUNK), dim3(256), 0, stream,
                       Cws, fnw, lng, lnb, out, n0);
  }
}